// Round 14
// baseline (591.026 us; speedup 1.0000x reference)
//
#include <hip/hip_runtime.h>
#include <hip/hip_bf16.h>

#define NTOK 4096
#define HID 2048
#define INTER 1408
#define NEXP 8
#define NPAIR 8192   // NTOK * TOP_K
#define NK1 64       // HID/32   (gemm1 BK=32)
#define NK2 44       // INTER/32 (gemm2 BK=32)
#define G1B 32768    // gemm1 bytes/buffer: A 256x32 bf16 (16K) + B 256x32 (16K)
#define G2SZ 24576   // gemm2 bytes/buffer: A 128x32 (8K) + B 256x32 (16K)

typedef short bf16x8 __attribute__((ext_vector_type(8)));
typedef float f32x4 __attribute__((ext_vector_type(4)));
typedef unsigned u32x4 __attribute__((ext_vector_type(4)));

__device__ __forceinline__ unsigned short f2bf(float f) {
  unsigned u = __builtin_bit_cast(unsigned, f);
  u += 0x7fffu + ((u >> 16) & 1u);   // round-to-nearest-even
  return (unsigned short)(u >> 16);
}
__device__ __forceinline__ float bf2f(unsigned short v) {
  return __builtin_bit_cast(float, (unsigned)v << 16);
}
__device__ __forceinline__ unsigned pk2(float lo, float hi) {
  return (unsigned)f2bf(lo) | ((unsigned)f2bf(hi) << 16);
}
__device__ __forceinline__ bf16x8 cvt8(float4 a, float4 b) {
  u32x4 u = { pk2(a.x, a.y), pk2(a.z, a.w), pk2(b.x, b.y), pk2(b.z, b.w) };
  return __builtin_bit_cast(bf16x8, u);
}

__device__ __forceinline__ void gload16(const void* g, void* l) {
  __builtin_amdgcn_global_load_lds(
      (const __attribute__((address_space(1))) void*)g,
      (__attribute__((address_space(3))) void*)l, 16, 0, 0);
}

// m204 bijective XCD swizzle over the LIVE grid size nwg.
__device__ __forceinline__ int xcd_swz(int lin, int nwg) {
  int xcd = lin & 7, base = lin >> 3;
  int q = nwg >> 3, r = nwg & 7;
  return (xcd < r ? xcd * (q + 1) : r * (q + 1) + (xcd - r) * q) + base;
}

#define BAR __builtin_amdgcn_s_barrier()
#define SCHED0 __builtin_amdgcn_sched_barrier(0)
#define LGKM0 asm volatile("s_waitcnt lgkmcnt(0)" ::: "memory")
#define VM3 asm volatile("s_waitcnt vmcnt(3)" ::: "memory")
#define VM0 asm volatile("s_waitcnt vmcnt(0)" ::: "memory")
#define PRIO1 __builtin_amdgcn_s_setprio(1)
#define PRIO0 __builtin_amdgcn_s_setprio(0)

// ============ routing only (no convert passes anymore) ============
// ctrl ints: [0..7]=cnt [8..15]=off [16]=T1 (BM=256, <=40) [17]=T2 (BM=128, <=72)
//   t1_e [32..71], t1_mt [72..111];  t2_e [112..183], t2_mt [184..255]
__global__ void k_route(const int* __restrict__ ids, int* __restrict__ ctrl,
                        unsigned short* __restrict__ row_token,
                        unsigned short* __restrict__ inv_row) {
  __shared__ int cnt[NEXP], cur[NEXP];
  int t = threadIdx.x;
  if (t < NEXP) cnt[t] = 0;
  __syncthreads();
  for (int p = t; p < NPAIR; p += 512) atomicAdd(&cnt[ids[p]], 1);
  __syncthreads();
  if (t == 0) {
    int acc = 0, T1 = 0, T2 = 0;
    for (int e = 0; e < NEXP; ++e) {
      cur[e] = acc;
      ctrl[e] = cnt[e];
      ctrl[8 + e] = acc;
      int n1 = (cnt[e] + 255) >> 8;
      for (int m = 0; m < n1; ++m) { ctrl[32 + T1] = e; ctrl[72 + T1] = m; ++T1; }
      int n2 = (cnt[e] + 127) >> 7;
      for (int m = 0; m < n2; ++m) { ctrl[112 + T2] = e; ctrl[184 + T2] = m; ++T2; }
      acc += cnt[e];
    }
    ctrl[16] = T1;
    ctrl[17] = T2;
  }
  __syncthreads();
  for (int p = t; p < NPAIR; p += 512) {
    int e = ids[p];
    int pos = atomicAdd(&cur[e], 1);
    row_token[pos] = (unsigned short)(p >> 1);
    inv_row[p] = (unsigned short)pos;
  }
}

// ================= GEMM1: gate_up + SwiGLU, fp32 inputs, reg-staged ========
// BM=256 rows x 128 acts (256 gate_up chans), BK=32, 8 waves (2Mx4N).
// A (gathered hs fp32) and B (w1 fp32) staged: global float4 loads -> regs ->
// cvt8 -> ds_write_b128 into the PROVEN bf16 64B-row chunk-XOR layout
// (0 bank conflicts, r12). No manual vmcnt: every staged datum is a register
// dependency, so the compiler inserts exact waits (avoids r5's mixed-class
// counted-vmcnt bug). 2 LDS buffers x 32KB; 2 phases/K-tile, 1 barrier each;
// loads issued 2 phases before their cvt+write (static even/odd reg sets).
// Hazard schedule (tile kt even, cur=P0, oth=P1):
//  ph0: rd A-lo,B(P0) | wr A(kt+1)->P1 | issue A(kt+2) | BAR | 16 MFMA
//  ph1: rd A-hi(P0)   | wr B(kt+1)->P1 | issue B(kt+2) | BAR | 16 MFMA
// P1-A old content (kt-1) last read at kt-1.ph1 -> write @kt.ph0 OK;
// P1-B old last read kt-1.ph0 -> write @kt.ph1 OK; consumer reads >=1 BAR later.

#define G1_LOAD(F, P, kt) { \
  const float* p_ = (P) + (size_t)(kt) * 32; \
  F[0] = *(const float4*)(p_ + c0); F[1] = *(const float4*)(p_ + c0 + 4); \
  F[2] = *(const float4*)(p_ + c1); F[3] = *(const float4*)(p_ + c1 + 4); }

#define G1_WRA(BB, F) { \
  *(bf16x8*)(smem + (BB) + wdA)      = cvt8(F[0], F[1]); \
  *(bf16x8*)(smem + (BB) + wdA + 16) = cvt8(F[2], F[3]); }
#define G1_WRB(BB, F) { \
  *(bf16x8*)(smem + (BB) + wdB)      = cvt8(F[0], F[1]); \
  *(bf16x8*)(smem + (BB) + wdB + 16) = cvt8(F[2], F[3]); }

#define G1_RDLO(BB) { \
  _Pragma("unroll") for (int m_ = 0; m_ < 4; ++m_) \
    af[m_] = *(const bf16x8*)(smem + (BB) + aoff + m_*1024 + swz); \
  _Pragma("unroll") for (int n_ = 0; n_ < 2; ++n_) { \
    bg[n_] = *(const bf16x8*)(smem + (BB) + bgoff + n_*1024 + swz); \
    bu[n_] = *(const bf16x8*)(smem + (BB) + buoff + n_*1024 + swz); } }
#define G1_RDHI(BB) { \
  _Pragma("unroll") for (int m_ = 0; m_ < 4; ++m_) \
    af[m_] = *(const bf16x8*)(smem + (BB) + aoff + 4096 + m_*1024 + swz); }

#define G1_MMALO \
  _Pragma("unroll") for (int m_ = 0; m_ < 4; ++m_) \
  _Pragma("unroll") for (int n_ = 0; n_ < 2; ++n_) { \
    acc[m_][n_]     = __builtin_amdgcn_mfma_f32_16x16x32_bf16(af[m_], bg[n_], acc[m_][n_], 0, 0, 0); \
    acc[m_][2 + n_] = __builtin_amdgcn_mfma_f32_16x16x32_bf16(af[m_], bu[n_], acc[m_][2 + n_], 0, 0, 0); }
#define G1_MMAHI \
  _Pragma("unroll") for (int m_ = 0; m_ < 4; ++m_) \
  _Pragma("unroll") for (int n_ = 0; n_ < 2; ++n_) { \
    acc[4 + m_][n_]     = __builtin_amdgcn_mfma_f32_16x16x32_bf16(af[m_], bg[n_], acc[4 + m_][n_], 0, 0, 0); \
    acc[4 + m_][2 + n_] = __builtin_amdgcn_mfma_f32_16x16x32_bf16(af[m_], bu[n_], acc[4 + m_][2 + n_], 0, 0, 0); }

__global__ __launch_bounds__(512, 2) void k_gemm1(
    const float* __restrict__ hsF,
    const float* __restrict__ w1F,
    const float* __restrict__ w2f,
    unsigned short* __restrict__ w2b,
    const int* __restrict__ ctrl,
    const unsigned short* __restrict__ row_token,
    unsigned short* __restrict__ act) {
  const int T1 = ctrl[16];
  const int nwg = T1 * 11;
  const int lin = blockIdx.x;
  if (lin >= nwg) {
    // ---- w2 fp32 -> bf16 convert (tail blocks, fill idle CUs) ----
    const int NW2 = NEXP * HID * INTER / 4;
    int nc = gridDim.x - nwg;
    for (int i = (lin - nwg) * 512 + threadIdx.x; i < NW2; i += nc * 512) {
      float4 v = reinterpret_cast<const float4*>(w2f)[i];
      ushort4 u;
      u.x = f2bf(v.x); u.y = f2bf(v.y); u.z = f2bf(v.z); u.w = f2bf(v.w);
      reinterpret_cast<ushort4*>(w2b)[i] = u;
    }
    return;
  }
  const int wg = xcd_swz(lin, nwg);
  const int ti = wg / 11;
  const int nt = wg - ti * 11;
  const int e = ctrl[32 + ti], mt = ctrl[72 + ti];
  const int rows = ctrl[e], off_e = ctrl[8 + e];
  const int n0g = nt * 128;
  const float* w1e = w1F + (size_t)e * (2 * INTER * HID);

  __shared__ __align__(16) char smem[2 * G1B];  // 64 KiB

  const int t = threadIdx.x;
  const int lane = t & 63, wv = t >> 6;
  const int wm = wv >> 2, wn = wv & 3;
  const int lm = lane & 15, hi4 = lane >> 4;
  const int swz = (hi4 ^ ((lm >> 1) & 3)) * 16;
  const int aoff = wm * 8192 + lm * 64;            // + mh*4096 + m*1024
  const int bgoff = 16384 + wn * 2048 + lm * 64;
  const int buoff = 24576 + wn * 2048 + lm * 64;

  // stage mapping: thread t -> row/chan r = t>>1, half h = t&1 (2 chunks).
  // LDS chunk q of row r holds global chunk q ^ ((r>>1)&3)  (r12-proven).
  const int r = t >> 1, h = t & 1;
  const int s4 = (t >> 2) & 3;                      // (r>>1)&3
  const int c0 = ((2 * h) ^ s4) * 8;                // float offsets
  const int c1 = ((2 * h + 1) ^ s4) * 8;
  const int wdA = r * 64 + h * 32;
  const int wdB = 16384 + r * 64 + h * 32;

  const float* aP;
  {
    int grow = mt * 256 + r;
    if (grow > rows - 1) grow = rows - 1;
    aP = hsF + (size_t)row_token[off_e + grow] * HID;
  }
  const float* bP;
  {
    int cg = (r < 128) ? (n0g + r) : (INTER + n0g + (r - 128));
    bP = w1e + (size_t)cg * HID;
  }

  f32x4 acc[8][4];
#pragma unroll
  for (int i = 0; i < 8; ++i)
#pragma unroll
    for (int j = 0; j < 4; ++j) acc[i][j] = (f32x4){0.f, 0.f, 0.f, 0.f};
  bf16x8 af[4], bg[2], bu[2];
  float4 fA0[4], fB0[4], fA1[4], fB1[4];

  // prologue: tiles 0,1 loaded to regs; tile 0 written to P0.
  G1_LOAD(fA0, aP, 0) G1_LOAD(fB0, bP, 0)
  G1_LOAD(fA1, aP, 1) G1_LOAD(fB1, bP, 1)
  G1_WRA(0, fA0) G1_WRB(0, fB0)
  LGKM0; BAR;

  for (int kt = 0; kt < NK1; kt += 2) {
    const bool l2 = (kt + 2) < NK1, l3 = (kt + 3) < NK1;
    // ---- even tile kt: cur P0, oth P1 ----
    G1_RDLO(0)
    G1_WRA(G1B, fA1)
    if (l2) { G1_LOAD(fA0, aP, kt + 2) }
    LGKM0; BAR;
    PRIO1; G1_MMALO PRIO0;

    G1_RDHI(0)
    G1_WRB(G1B, fB1)
    if (l2) { G1_LOAD(fB0, bP, kt + 2) }
    LGKM0; BAR;
    PRIO1; G1_MMAHI PRIO0;

    // ---- odd tile kt+1: cur P1, oth P0 ----
    G1_RDLO(G1B)
    if (l2) { G1_WRA(0, fA0) }
    if (l3) { G1_LOAD(fA1, aP, kt + 3) }
    LGKM0; BAR;
    PRIO1; G1_MMALO PRIO0;

    G1_RDHI(G1B)
    if (l2) { G1_WRB(0, fB0) }
    if (l3) { G1_LOAD(fB1, bP, kt + 3) }
    LGKM0; BAR;
    PRIO1; G1_MMAHI PRIO0;
  }

  // SwiGLU epilogue: gate = acc[mh*4+m][n], up = acc[mh*4+m][2+n]
#pragma unroll
  for (int mh = 0; mh < 2; ++mh)
#pragma unroll
    for (int m = 0; m < 4; ++m)
#pragma unroll
      for (int n = 0; n < 2; ++n) {
        int col = n0g + wn * 32 + n * 16 + lm;
#pragma unroll
        for (int j = 0; j < 4; ++j) {
          int grow = mt * 256 + wm * 128 + mh * 64 + m * 16 + hi4 * 4 + j;
          if (grow < rows) {
            float g = acc[mh * 4 + m][n][j];
            float u = acc[mh * 4 + m][2 + n][j];
            float a = g / (1.0f + __expf(-g)) * u;
            act[(size_t)(off_e + grow) * INTER + col] = f2bf(a);
          }
        }
      }
}

// ================= GEMM2: down proj (r13-proven, BM=128 x 256 cols) ========
// BK=32, 8 waves, 48 KiB dbuf, (512,4); counted 2-deep VM3 pipeline.
#define T_STAGE(BB, kt) { \
  gload16(aptr + (size_t)(kt)*32, smem + (BB) + wvb16); \
  gload16(bptr0 + (size_t)(kt)*32, smem + (BB) + 8192 + wvb16); \
  gload16(bptr1 + (size_t)(kt)*32, smem + (BB) + 16384 + wvb16); }

#define T_RD(BB) { \
  _Pragma("unroll") for (int m_ = 0; m_ < 4; ++m_) \
    af[m_] = *(const bf16x8*)(smem + (BB) + arow + m_*1024 + swz); \
  _Pragma("unroll") for (int n_ = 0; n_ < 2; ++n_) { \
    b0[n_] = *(const bf16x8*)(smem + (BB) + brow + n_*1024 + swz); \
    b1[n_] = *(const bf16x8*)(smem + (BB) + brow + 8192 + n_*1024 + swz); } }

#define T_MMA \
  _Pragma("unroll") for (int m_ = 0; m_ < 4; ++m_) \
  _Pragma("unroll") for (int n_ = 0; n_ < 2; ++n_) { \
    acc0[m_][n_] = __builtin_amdgcn_mfma_f32_16x16x32_bf16(af[m_], b0[n_], acc0[m_][n_], 0, 0, 0); \
    acc1[m_][n_] = __builtin_amdgcn_mfma_f32_16x16x32_bf16(af[m_], b1[n_], acc1[m_][n_], 0, 0, 0); }

__global__ __launch_bounds__(512, 4) void k_gemm2(
    const unsigned short* __restrict__ act,
    const unsigned short* __restrict__ w2,
    const int* __restrict__ ctrl,
    unsigned short* __restrict__ eo) {
  const int T2 = ctrl[17];
  const int nwg = T2 * 8;
  const int lin = blockIdx.x;
  if (lin >= nwg) return;
  const int wg = xcd_swz(lin, nwg);
  const int ti = wg >> 3;
  const int nt = wg & 7;
  const int e = ctrl[112 + ti], mt = ctrl[184 + ti];
  const int rows = ctrl[e], off_e = ctrl[8 + e];
  const int n0 = nt * 256;
  const unsigned short* w2e = w2 + (size_t)e * (HID * INTER);

  __shared__ __align__(16) char smem[2 * G2SZ];  // 48 KiB

  const int t = threadIdx.x;
  const int lane = t & 63, wv = t >> 6;
  const int wm = wv >> 2, wn = wv & 3;
  const int lm = lane & 15, hi4 = lane >> 4;
  const int wvb16 = (t & 448) * 16;
  const int arow = wm * 4096 + lm * 64;
  const int brow = 8192 + wn * 2048 + lm * 64;
  const int swz = (hi4 ^ ((lm >> 1) & 3)) * 16;

  const unsigned short *aptr, *bptr0, *bptr1;
  {
    int cl8 = ((t & 3) ^ ((t >> 3) & 3)) * 8;
    int r = t >> 2;                       // 0..127
    int g0 = mt * 128 + r; if (g0 > rows - 1) g0 = rows - 1;
    aptr = act + (size_t)(off_e + g0) * INTER + cl8;       // contiguous rows
    bptr0 = w2e + (size_t)(n0 + r) * INTER + cl8;          // cols n0+0..127
    bptr1 = w2e + (size_t)(n0 + 128 + r) * INTER + cl8;    // cols n0+128..255
  }

  f32x4 acc0[4][2], acc1[4][2];
#pragma unroll
  for (int m = 0; m < 4; ++m)
#pragma unroll
    for (int n = 0; n < 2; ++n) {
      acc0[m][n] = (f32x4){0.f, 0.f, 0.f, 0.f};
      acc1[m][n] = (f32x4){0.f, 0.f, 0.f, 0.f};
    }
  bf16x8 af[4], b0[2], b1[2];

  T_STAGE(0, 0)
  T_STAGE(G2SZ, 1)
  VM3; BAR;
  unsigned cur = 0, oth = G2SZ;
  for (int kt = 0; kt < NK2; ++kt) {
    T_RD(cur)
    LGKM0; BAR;
    SCHED0;
    if (kt + 2 < NK2) { T_STAGE(cur, kt + 2) }
    PRIO1; T_MMA PRIO0;
    if (kt < NK2 - 2) { VM3; BAR; }
    else if (kt == NK2 - 2) { VM0; BAR; }
    unsigned tmp = cur; cur = oth; oth = tmp;
  }

#pragma unroll
  for (int m = 0; m < 4; ++m)
#pragma unroll
    for (int n = 0; n < 2; ++n) {
      int col = n0 + wn * 32 + n * 16 + lm;
#pragma unroll
      for (int j = 0; j < 4; ++j) {
        int grow = mt * 128 + wm * 64 + m * 16 + hi4 * 4 + j;
        if (grow < rows) {
          size_t base = (size_t)(off_e + grow) * HID;
          eo[base + col] = f2bf(acc0[m][n][j]);
          eo[base + col + 128] = f2bf(acc1[m][n][j]);
        }
      }
    }
}

// ---------------- weighted combine: out = w0*eo[r0] + w1*eo[r1] ----------
__global__ void k_combine(const unsigned short* __restrict__ eo,
                          const float* __restrict__ tw,
                          const unsigned short* __restrict__ inv_row,
                          float* __restrict__ out) {
  int idx = blockIdx.x * blockDim.x + threadIdx.x;  // one bf16x8 chunk
  int tok = idx >> 8;        // HID/8 = 256 chunks per token
  int c8 = (idx & 255) * 8;
  int r0 = inv_row[tok * 2], r1 = inv_row[tok * 2 + 1];
  float w0 = tw[tok * 2], w1 = tw[tok * 2 + 1];
  bf16x8 v0 = *(const bf16x8*)(eo + (size_t)r0 * HID + c8);
  bf16x8 v1 = *(const bf16x8*)(eo + (size_t)r1 * HID + c8);
  float4 o0, o1;
  o0.x = w0 * bf2f((unsigned short)v0[0]) + w1 * bf2f((unsigned short)v1[0]);
  o0.y = w0 * bf2f((unsigned short)v0[1]) + w1 * bf2f((unsigned short)v1[1]);
  o0.z = w0 * bf2f((unsigned short)v0[2]) + w1 * bf2f((unsigned short)v1[2]);
  o0.w = w0 * bf2f((unsigned short)v0[3]) + w1 * bf2f((unsigned short)v1[3]);
  o1.x = w0 * bf2f((unsigned short)v0[4]) + w1 * bf2f((unsigned short)v1[4]);
  o1.y = w0 * bf2f((unsigned short)v0[5]) + w1 * bf2f((unsigned short)v1[5]);
  o1.z = w0 * bf2f((unsigned short)v0[6]) + w1 * bf2f((unsigned short)v1[6]);
  o1.w = w0 * bf2f((unsigned short)v0[7]) + w1 * bf2f((unsigned short)v1[7]);
  float4* op = reinterpret_cast<float4*>(out) + (size_t)tok * 512 + (idx & 255) * 2;
  op[0] = o0;
  op[1] = o1;
}

extern "C" void kernel_launch(void* const* d_in, const int* in_sizes, int n_in,
                              void* d_out, int out_size, void* d_ws, size_t ws_size,
                              hipStream_t stream) {
  const float* hs_f = (const float*)d_in[0];
  const float* w1_f = (const float*)d_in[1];
  const float* w2_f = (const float*)d_in[2];
  const float* tw   = (const float*)d_in[3];
  const int*   tids = (const int*)d_in[4];
  float* out = (float*)d_out;

  // workspace layout (bytes) — same proven 178,323,712-byte footprint
  // (hs_b/w1_b slots now unused; weights consumed fp32 directly by gemm1).
  char* ws = (char*)d_ws;
  unsigned short* w2_b = (unsigned short*)(ws + 109051904);       // 46,137,344
  unsigned short* act  = (unsigned short*)(ws + 155189248);       // 23,068,672
  unsigned short* eo   = (unsigned short*)(ws + 16777216);        // 33,554,432
  int* ctrl = (int*)(ws + 178257920);                             // 1024 B
  unsigned short* row_token = (unsigned short*)(ws + 178258944);  // 16,384
  unsigned short* inv_row   = (unsigned short*)(ws + 178275328);  // 16,384

  k_route<<<1, 512, 0, stream>>>(tids, ctrl, row_token, inv_row);

  // gemm1: 8-phase... reg-staged BM=256 tiles (nwg = T1*11 <= 440);
  // tail blocks convert w2 fp32->bf16 for gemm2.
  k_gemm1<<<1024, 512, 0, stream>>>(hs_f, w1_f, w2_f, w2_b, ctrl, row_token, act);
  // gemm2: 256-wide output tiles -> T2*8 blocks (~512 = one dispatch round)
  k_gemm2<<<72 * 8, 512, 0, stream>>>(act, w2_b, ctrl, eo);
  k_combine<<<NTOK * HID / 8 / 256, 256, 0, stream>>>(eo, tw, inv_row, out);
}